// Round 10
// baseline (208.532 us; speedup 1.0000x reference)
//
#include <hip/hip_runtime.h>

#define D_IN_   50937
#define D_LYR_  50425
#define NCH     24
#define NBE     16
#define NME     128
#define NOUT    168
#define NPAD    192
#define KROWS   50688        // padded GEMM K: 256 melody + 50432 lyrics (mult of 64)
#define KSPLIT  16
#define TOTSTEP 792          // KROWS/64
#define PARTN   (2048*168)   // 344064

typedef __attribute__((ext_vector_type(8))) short short8;
typedef __attribute__((ext_vector_type(4))) float f32x4;
typedef float f32x4u __attribute__((ext_vector_type(4), aligned(4)));
typedef __attribute__((ext_vector_type(2))) unsigned int u32x2;

static __device__ __forceinline__ unsigned short f2bf(float f) {
    unsigned int u = __float_as_uint(f);
    u += 0x7FFF + ((u >> 16) & 1);          // round-to-nearest-even
    return (unsigned short)(u >> 16);
}
static __device__ __forceinline__ unsigned int pack2(float x, float y) {
    return (unsigned int)f2bf(x) | ((unsigned int)f2bf(y) << 16);
}

// scalar W[d][n] over concatenated heads
static __device__ __forceinline__ float wsrc(const float* wc, const float* wb,
                                             const float* wm, int d, int n) {
    if (n < NCH)        return wc[d * NCH + n];
    if (n < NCH + NBE)  return wb[d * NBE + (n - NCH)];
    if (n < NOUT)       return wm[(long)d * NME + (n - NCH - NBE)];
    return 0.f;
}
// quad W[d][n0..n0+3]; head boundaries (24,40,168) are 4-aligned so quads never straddle
static __device__ __forceinline__ f32x4 wsrc4(const float* wc, const float* wb,
                                              const float* wm, int d, int nq) {
    int n0 = nq * 4;
    if (n0 < 24)  return *(const f32x4*)(wc + d * 24 + n0);
    if (n0 < 40)  return *(const f32x4*)(wb + d * 16 + (n0 - 24));
    if (n0 < 168) return *(const f32x4*)(wm + (long)d * 128 + (n0 - 40));
    f32x4 z = {0.f, 0.f, 0.f, 0.f};
    return z;
}

// folded, transposed, bf16 weights: wbt[n][r], r = d-256
__global__ __launch_bounds__(256) void k_fold(const float* wc, const float* wb,
                                              const float* wm_, const float* conv_w,
                                              unsigned short* wbt) {
    __shared__ unsigned short tile[64 * 196];   // [dloc][n], pad 196 (8B-aligned rows)
    float cw0 = conv_w[3], cw1 = conv_w[4], cw2 = conv_w[5];
    int r0 = blockIdx.x * 64;
    int tid = threadIdx.x;
    for (int i = 0; i < 12; ++i) {
        int idx = tid + i * 256;                // 64 rows x 48 quads
        int dl = idx / 48, nq = idx % 48;
        int r = r0 + dl;
        f32x4 v = {0.f, 0.f, 0.f, 0.f};
        if (r < 50681) {                        // rows >= 50681 stay zero (pads A-tail)
            int d = 256 + r;
            f32x4 w0 = wsrc4(wc, wb, wm_, d, nq);
            f32x4 wn1 = wsrc4(wc, wb, wm_, d - 1, nq);
            v = cw1 * w0 + cw2 * wn1;
            if (d + 1 < D_IN_) v += cw0 * wsrc4(wc, wb, wm_, d + 1, nq);
        }
        u32x2 p; p.x = pack2(v.x, v.y); p.y = pack2(v.z, v.w);
        *(u32x2*)&tile[dl * 196 + nq * 4] = p;
    }
    __syncthreads();
    for (int i = 0; i < 6; ++i) {
        int idx = tid + i * 256;                // 192 n x 8 chunks
        int n = idx >> 3, ch = idx & 7;
        short8 o;
        for (int j = 0; j < 8; ++j) o[j] = (short)tile[(ch * 8 + j) * 196 + n];
        *(short8*)(wbt + (long)n * KROWS + r0 + ch * 8) = o;
    }
}

// C[j] = bias + ctx @ W'[0:256, j] (+ conv_b * colsum, generally zero); ctx fused in
__global__ void k_cvec(const int* genre, const int* tempo, const int* keysig,
                       const float* emb,
                       const float* wc, const float* wb, const float* wm_,
                       const float* conv_w, const float* conv_b,
                       const float* bc, const float* bb, const float* bm_, float* C) {
    int j = blockIdx.x;          // 0..167
    int lane = threadIdx.x;      // 64
    int g = genre[0], tt = tempo[0], kk = keysig[0];
    float cw0 = conv_w[3], cw1 = conv_w[4], cw2 = conv_w[5];
    float s = 0.f;
    for (int d = lane; d < 256; d += 64) {
        float cx = emb[g * 256 + d] + emb[(10 + tt) * 256 + d] +
                   emb[(20 + kk) * 256 + d] + emb[34 * 256 + d];
        float wp = cw1 * wsrc(wc, wb, wm_, d, j) + cw0 * wsrc(wc, wb, wm_, d + 1, j);
        if (d > 0) wp += cw2 * wsrc(wc, wb, wm_, d - 1, j);
        s += cx * wp;
    }
    float cb = conv_b[0];
    if (cb != 0.f) {
        float cs = 0.f;
        for (int d = lane; d < D_IN_; d += 64) cs += wsrc(wc, wb, wm_, d, j);
        s += cb * cs;
    }
    for (int off = 32; off; off >>= 1) s += __shfl_down(s, off);
    if (lane == 0) {
        float b = (j < NCH) ? bc[j] : (j < NCH + NBE) ? bb[j - NCH] : bm_[j - NCH - NBE];
        C[j] = s + b;
    }
}

// lgkm-only barrier: orders all LDS traffic across the workgroup WITHOUT
// draining vmcnt, so register-destined global loads stay in flight across
// phases (the __syncthreads vmcnt(0) drain was the per-phase latency stall).
#define LGKM_BARRIER()                                          \
    do {                                                        \
        asm volatile("s_waitcnt lgkmcnt(0)" ::: "memory");      \
        __builtin_amdgcn_s_barrier();                           \
        __builtin_amdgcn_sched_barrier(0);                      \
    } while (0)

// Split-K GEMM — R9 skeleton + lgkm-only barrier (A prefetch lives across phases):
//  - tile 64 rows x 192 cols x 64 K; 256 thr = 4 waves = 2M x 2N;
//    wave = 32 rows x 96 cols = 24 MFMA/phase, 16 outstanding dwordx4 A-loads.
//  - A: global->reg ping-pong (2 named regsets); vmcnt wait lands at next
//    phase's pack (compiler-inserted), NOT at the barrier.
//  - B: reg-staged double-buffered LDS (48 KB); its vmcnt wait is auto-forced
//    at the pre-barrier ds_write, covered by compute.
//  - grid 512 = 32 mb x 16 ks (XCD-pinned ks) = 2 blocks/CU.
__global__ __launch_bounds__(256, 2) void k_gemm(const float* mel, const float* lyr,
                                                 const unsigned short* wbt,
                                                 float* partial) {
    __shared__ unsigned short Bs[2 * NPAD * 64];   // 2 x 24 KB
    const int blk = blockIdx.x;
    const int ks = ((blk & 7) << 1) | ((blk >> 3) & 1);  // XCD x -> ks {2x,2x+1}
    const int bm = blk >> 4;                             // 0..31 (64-row tiles)
    const int tid = threadIdx.x, lane = tid & 63, wv = tid >> 6;
    const int wm = wv >> 1, wn = wv & 1;                 // 2 M-groups x 2 N-groups
    const int l15 = lane & 15, lk = lane >> 4;
    const int start = ks * 49 + (ks < 8 ? ks : 8);
    const int cnt = 49 + (ks < 8 ? 1 : 0);

    // per-wave A row bases: 2 frags (mi=0,1), rows bm*64 + wm*32 + mi*16 + l15
    const float* melB0 = mel + (bm * 64 + wm * 32 + l15) * 256;
    const float* melB1 = melB0 + 16 * 256;
    const float* lyrB0 = lyr + (long)(bm * 64 + wm * 32 + l15) * D_LYR_ - 256;
    const float* lyrB1 = lyrB0 + 16L * D_LYR_;

    // B-stage coords: 6 x short8 per thread (192 rows / 32 row-groups)
    const int bn = tid >> 3, bch = tid & 7;

    f32x4 acc[2][6];
    #pragma unroll
    for (int mi = 0; mi < 2; ++mi)
        #pragma unroll
        for (int ni = 0; ni < 6; ++ni) acc[mi][ni] = (f32x4){0.f, 0.f, 0.f, 0.f};

    auto loadA = [&](int t2, f32x4* dst) {   // dst[8] = [mi*4 + kk*2 + half]
        int gt = start + t2;
        int r0 = gt * 64;
        if (gt != TOTSTEP - 1) {             // uniform fast path
            #pragma unroll
            for (int kk = 0; kk < 2; ++kk) {
                int r = r0 + kk * 32 + lk * 8;
                const float* p0 = (r < 256) ? (melB0 + r) : (lyrB0 + r);
                const float* p1 = (r < 256) ? (melB1 + r) : (lyrB1 + r);
                dst[kk * 2]     = *(const f32x4u*)p0;
                dst[kk * 2 + 1] = *(const f32x4u*)(p0 + 4);
                dst[4 + kk * 2]     = *(const f32x4u*)p1;
                dst[4 + kk * 2 + 1] = *(const f32x4u*)(p1 + 4);
            }
        } else {                             // tail tile (block-uniform branch)
            #pragma unroll
            for (int kk = 0; kk < 2; ++kk) {
                int r = r0 + kk * 32 + lk * 8;
                int c = r - 256;
                const float* p0 = lyrB0 + r;
                const float* p1 = lyrB1 + r;
                f32x4 a0, a1, b0, b1;
                #pragma unroll
                for (int q = 0; q < 4; ++q) {
                    a0[q] = (c + q     < D_LYR_) ? p0[q]     : 0.f;
                    a1[q] = (c + 4 + q < D_LYR_) ? p0[4 + q] : 0.f;
                    b0[q] = (c + q     < D_LYR_) ? p1[q]     : 0.f;
                    b1[q] = (c + 4 + q < D_LYR_) ? p1[4 + q] : 0.f;
                }
                dst[kk * 2] = a0; dst[kk * 2 + 1] = a1;
                dst[4 + kk * 2] = b0; dst[4 + kk * 2 + 1] = b1;
            }
        }
    };

    auto loadBreg = [&](int t2, short8* brg) {   // 6 x 16B per thread, L2-resident
        int r0 = (start + t2) * 64;
        #pragma unroll
        for (int i = 0; i < 6; ++i) {
            int n = bn + i * 32;
            brg[i] = *(const short8*)(wbt + (long)n * KROWS + r0 + bch * 8);
        }
    };
    auto writeB = [&](const short8* brg, int buf) {
        char* Bb = (char*)Bs + buf * 24576;
        #pragma unroll
        for (int i = 0; i < 6; ++i) {
            int n = bn + i * 32;
            *(short8*)(Bb + n * 128 + ((bch * 16) ^ ((n & 7) << 4))) = brg[i];
        }
    };

    auto compute = [&](const f32x4* a, int buf) {
        const char* Bb = (const char*)Bs + buf * 24576;
        #pragma unroll
        for (int kk = 0; kk < 2; ++kk) {
            short8 af[2];
            #pragma unroll
            for (int mi = 0; mi < 2; ++mi) {
                f32x4 v0 = a[mi * 4 + kk * 2], v1 = a[mi * 4 + kk * 2 + 1];
                short8 o;
                o[0] = (short)f2bf(v0.x); o[1] = (short)f2bf(v0.y);
                o[2] = (short)f2bf(v0.z); o[3] = (short)f2bf(v0.w);
                o[4] = (short)f2bf(v1.x); o[5] = (short)f2bf(v1.y);
                o[6] = (short)f2bf(v1.z); o[7] = (short)f2bf(v1.w);
                af[mi] = o;
            }
            #pragma unroll
            for (int ni = 0; ni < 6; ++ni) {
                int n = wn * 96 + ni * 16 + l15;
                int byte = n * 128 + (((kk * 64) + lk * 16) ^ ((n & 7) << 4));
                short8 bf = *(const short8*)(Bb + byte);
                #pragma unroll
                for (int mi = 0; mi < 2; ++mi)
                    acc[mi][ni] = __builtin_amdgcn_mfma_f32_16x16x32_bf16(
                        af[mi], bf, acc[mi][ni], 0, 0, 0);
            }
        }
    };

    f32x4 rgA[8], rgB[8];
    // prologue: A(0) issued; B(0) staged into buf 0
    loadA(0, rgA);
    {
        short8 b0[6];
        loadBreg(0, b0);
        writeB(b0, 0);
    }
    LGKM_BARRIER();

    for (int t = 0;;) {
        {   // even phase: compute rgA from buf t&1
            bool pf = (t + 1 < cnt);
            short8 brg[6];
            if (pf) { loadA(t + 1, rgB); loadBreg(t + 1, brg); }
            compute(rgA, t & 1);
            if (!pf) break;
            writeB(brg, (t + 1) & 1);
            LGKM_BARRIER();
            ++t;
        }
        {   // odd phase: compute rgB
            bool pf = (t + 1 < cnt);
            short8 brg[6];
            if (pf) { loadA(t + 1, rgA); loadBreg(t + 1, brg); }
            compute(rgB, t & 1);
            if (!pf) break;
            writeB(brg, (t + 1) & 1);
            LGKM_BARRIER();
            ++t;
        }
    }

    // deterministic partial store
    float* pbase = partial + (long)ks * PARTN;
    #pragma unroll
    for (int mi = 0; mi < 2; ++mi) {
        int rb = bm * 64 + wm * 32 + mi * 16 + lk * 4;
        #pragma unroll
        for (int ni = 0; ni < 6; ++ni) {
            int col = wn * 96 + ni * 16 + l15;
            if (col < NOUT) {
                #pragma unroll
                for (int q = 0; q < 4; ++q)
                    pbase[(long)(rb + q) * NOUT + col] = acc[mi][ni][q];
            }
        }
    }
}

__global__ void k_reduce(const float* partial, const float* C, float* out) {
    int idx = blockIdx.x * 256 + threadIdx.x;    // vec4 index
    if (idx >= PARTN / 4) return;
    int base = idx * 4;
    f32x4 s;
    for (int q = 0; q < 4; ++q) s[q] = C[(base + q) % NOUT];
    for (int ks = 0; ks < KSPLIT; ++ks)
        s += *(const f32x4*)(partial + (long)ks * PARTN + base);
    *(f32x4*)(out + base) = s;
}

extern "C" void kernel_launch(void* const* d_in, const int* in_sizes, int n_in,
                              void* d_out, int out_size, void* d_ws, size_t ws_size,
                              hipStream_t stream) {
    const int*   genre   = (const int*)d_in[0];
    const int*   tempo   = (const int*)d_in[1];
    const int*   keysig  = (const int*)d_in[2];
    const float* mel     = (const float*)d_in[4];
    const float* lyr     = (const float*)d_in[5];
    const float* emb     = (const float*)d_in[6];
    const float* conv_w  = (const float*)d_in[7];
    const float* conv_b  = (const float*)d_in[8];
    const float* w_chord = (const float*)d_in[9];
    const float* b_chord = (const float*)d_in[10];
    const float* w_beat  = (const float*)d_in[11];
    const float* b_beat  = (const float*)d_in[12];
    const float* w_mel   = (const float*)d_in[13];
    const float* b_mel   = (const float*)d_in[14];

    char* ws = (char*)d_ws;
    unsigned short* wbt = (unsigned short*)ws;              // 192*50688*2 = 19,464,192 B
    float* Cvec    = (float*)(ws + 19464192);               // 1 KB
    float* partial = (float*)(ws + 19466240);               // 16*344064*4 = 22,020,096 B
    float* out     = (float*)d_out;

    hipLaunchKernelGGL(k_fold, dim3(TOTSTEP), dim3(256), 0, stream,
                       w_chord, w_beat, w_mel, conv_w, wbt);
    hipLaunchKernelGGL(k_cvec, dim3(NOUT), dim3(64), 0, stream,
                       genre, tempo, keysig, emb,
                       w_chord, w_beat, w_mel, conv_w, conv_b,
                       b_chord, b_beat, b_mel, Cvec);
    hipLaunchKernelGGL(k_gemm, dim3(512), dim3(256), 0, stream,
                       mel, lyr, wbt, partial);
    hipLaunchKernelGGL(k_reduce, dim3((PARTN / 4 + 255) / 256), dim3(256), 0, stream,
                       partial, Cvec, out);
}